// Round 6
// baseline (1014.002 us; speedup 1.0000x reference)
//
#include <hip/hip_runtime.h>

#define NN 100000
#define NE 1600000
#define DIM 128
#define NT 13            // src tiles: src>>13 -> 8192 rows = 2 MB bf16 per tile (fits 4 MB L2)
#define SH 13
#define LEN (NN * NT)    // 1,300,000 bucket counters
#define NB_SCAN ((LEN + 1023) / 1024)   // 1270 scan blocks

typedef __attribute__((ext_vector_type(8))) short short8;
typedef __attribute__((ext_vector_type(4))) float f4;
typedef __attribute__((ext_vector_type(4))) unsigned u4;

__device__ __forceinline__ unsigned short f2bf(float f){
  unsigned x = __float_as_uint(f);
  x += 0x7fffu + ((x >> 16) & 1u);
  return (unsigned short)(x >> 16);
}
__device__ __forceinline__ unsigned pack2(float lo, float hi){
  return ((unsigned)f2bf(hi) << 16) | (unsigned)f2bf(lo);
}
__device__ __forceinline__ float blo(unsigned u){ return __uint_as_float(u << 16); }
__device__ __forceinline__ float bhi(unsigned u){ return __uint_as_float(u & 0xffff0000u); }

// ---------------- fallback sentinel (ws too small diagnostic) ----------------
__global__ void k_sentinel(float* __restrict__ out, int n){
  int i = blockIdx.x * blockDim.x + threadIdx.x;
  if (i < n) out[i] = 12345.0f;
}

// ---------------- x fp32 -> bf16x2 (each thread: 8 floats -> 16 B out) ------
__global__ void k_cvt(const float* __restrict__ x, unsigned* __restrict__ xb){
  int i = blockIdx.x * blockDim.x + threadIdx.x;   // i < NN*16  (r5 bug: was NN*32 -> 25.6MB OOB write)
  if (i >= NN * 16) return;
  f4 a = ((const f4*)x)[2 * i];
  f4 b = ((const f4*)x)[2 * i + 1];
  u4 o;
  o[0] = pack2(a[0], a[1]); o[1] = pack2(a[2], a[3]);
  o[2] = pack2(b[0], b[1]); o[3] = pack2(b[2], b[3]);
  ((u4*)xb)[i] = o;
}

// ---------------- bucketed CSR build ----------------
__global__ void k_hist(const int* __restrict__ src, const int* __restrict__ dst,
                       int* __restrict__ cnt){
  int i = blockIdx.x * blockDim.x + threadIdx.x;
  if (i < NE) atomicAdd(&cnt[dst[i] * NT + (src[i] >> SH)], 1);
}

__global__ void k_bsum(const int* __restrict__ cnt, int* __restrict__ bsum, int len){
  __shared__ int sh[256];
  int t = threadIdx.x, b = blockIdx.x;
  int base = b * 1024 + t * 4;
  int s = 0;
  #pragma unroll
  for (int j = 0; j < 4; ++j){ int i = base + j; if (i < len) s += cnt[i]; }
  sh[t] = s; __syncthreads();
  for (int off = 128; off > 0; off >>= 1){
    if (t < off) sh[t] += sh[t + off];
    __syncthreads();
  }
  if (t == 0) bsum[b] = sh[0];
}

__global__ void k_scanp(const int* __restrict__ bsum, int* __restrict__ boff, int nb){
  __shared__ int sh[256];
  int t = threadIdx.x;
  int chunk = (nb + 255) / 256;
  int s = 0;
  for (int j = 0; j < chunk; ++j){ int i = t * chunk + j; if (i < nb) s += bsum[i]; }
  sh[t] = s; __syncthreads();
  int tin = s;
  for (int off = 1; off < 256; off <<= 1){
    int u = (t >= off) ? sh[t - off] : 0;
    __syncthreads();
    sh[t] += u;
    __syncthreads();
  }
  int run = sh[t] - tin;   // exclusive prefix for this thread's chunk
  for (int j = 0; j < chunk; ++j){
    int i = t * chunk + j;
    if (i < nb){ boff[i] = run; run += bsum[i]; }
  }
}

__global__ void k_scanf(const int* __restrict__ cnt, const int* __restrict__ boff,
                        int* __restrict__ rp, int* __restrict__ pos, int len){
  __shared__ int sh[256];
  int t = threadIdx.x, b = blockIdx.x;
  int base = b * 1024 + t * 4;
  int c[4]; int s = 0;
  #pragma unroll
  for (int j = 0; j < 4; ++j){ int i = base + j; c[j] = (i < len) ? cnt[i] : 0; s += c[j]; }
  sh[t] = s; __syncthreads();
  int tin = s;
  for (int off = 1; off < 256; off <<= 1){
    int u = (t >= off) ? sh[t - off] : 0;
    __syncthreads();
    sh[t] += u;
    __syncthreads();
  }
  int run = boff[b] + sh[t] - tin;
  #pragma unroll
  for (int j = 0; j < 4; ++j){
    int i = base + j;
    if (i < len){
      rp[i] = run; pos[i] = run; run += c[j];
      if (i == len - 1) rp[len] = run;
    }
  }
}

__global__ void k_scatter(const int* __restrict__ src, const int* __restrict__ dst,
                          int* __restrict__ pos, int* __restrict__ ss){
  int i = blockIdx.x * blockDim.x + threadIdx.x;
  if (i < NE){
    int s = src[i];
    int p = atomicAdd(&pos[dst[i] * NT + (s >> SH)], 1);
    ss[p] = s;
  }
}

// ---------------- W packing: fp32 -> bf16 MFMA B-fragment order ----------------
template<int NB16>
__global__ void k_pack(const float* __restrict__ Wl,
                       const float* __restrict__ Wr,
                       unsigned short* __restrict__ Bp){
  constexpr int DOUT = NB16 * 16;
  int idx = blockIdx.x * blockDim.x + threadIdx.x;
  if (idx >= 8 * NB16 * 64) return;
  int lane = idx & 63;
  int nb = (idx >> 6) % NB16;
  int ks = idx / (64 * NB16);
  int n = nb * 16 + (lane & 15);
  int k0 = ks * 32 + (lane >> 4) * 8;
  short8 v;
  #pragma unroll
  for (int j = 0; j < 8; ++j){
    int k = k0 + j;
    float w = (k < 128) ? Wl[k * DOUT + n] : Wr[(k - 128) * DOUT + n];
    v[j] = (short)f2bf(w);
  }
  ((short8*)Bp)[idx] = v;
}

// ---------------- fused tiled mean-aggregate + dual-GEMM (+BN+ReLU) ----------------
// Block = 32 rows. Phase 1: tile-major sweep (t outer) over src-buckets so all
// concurrent blocks keep the same ~2 MB src tile L2-resident; per-wave fp32
// accumulators for 8 rows persist across tiles. Phase 2: MFMA 16x16x32 bf16,
// K 0..127 = mean@Wl (LDS), K 128..255 = h@Wr (global rows).
template<int NB16, bool DO_BN>
__global__ __launch_bounds__(256)
void k_fused(const unsigned* __restrict__ Xb,
             const int* __restrict__ rp2, const int* __restrict__ ss,
             const unsigned short* __restrict__ Bp,
             const float* __restrict__ bias,
             const float* __restrict__ bg, const float* __restrict__ bb,
             const float* __restrict__ bm, const float* __restrict__ bv,
             unsigned short* __restrict__ OutB, float* __restrict__ OutF){
  constexpr int DOUT = NB16 * 16;
  constexpr int NBW = NB16 / 4;
  __shared__ unsigned smA[32][68];
  const int t = threadIdx.x;
  const int lane = t & 63;
  const int wv = t >> 6;
  const int m0 = blockIdx.x * 32;
  const int row0 = m0 + wv * 8;

  // ---- phase 1: tiled mean aggregation ----
  float ax[8], ay[8];
  int cur[8];
  #pragma unroll
  for (int rr = 0; rr < 8; ++rr){
    ax[rr] = 0.f; ay[rr] = 0.f;
    cur[rr] = rp2[(row0 + rr) * NT];
  }
  for (int tt = 0; tt < NT; ++tt){
    #pragma unroll
    for (int rr = 0; rr < 8; ++rr){
      int end = rp2[(row0 + rr) * NT + tt + 1];
      int e = cur[rr];
      for (; e + 2 <= end; e += 2){
        int s0 = ss[e], s1 = ss[e + 1];
        unsigned u0 = Xb[(size_t)s0 * 64 + lane];
        unsigned u1 = Xb[(size_t)s1 * 64 + lane];
        ax[rr] += blo(u0) + blo(u1);
        ay[rr] += bhi(u0) + bhi(u1);
      }
      if (e < end){
        unsigned u = Xb[(size_t)ss[e] * 64 + lane];
        ax[rr] += blo(u); ay[rr] += bhi(u);
      }
      cur[rr] = end;
    }
  }
  #pragma unroll
  for (int rr = 0; rr < 8; ++rr){
    int row = row0 + rr;
    int d = rp2[(row + 1) * NT] - rp2[row * NT];
    float inv = (d > 0) ? 1.f / (float)d : 0.f;
    smA[wv * 8 + rr][lane] = pack2(ax[rr] * inv, ay[rr] * inv);
  }
  __syncthreads();

  // ---- phase 2: dual GEMM ----
  const int q = lane >> 4, lr = lane & 15;
  const short8* pb = (const short8*)Bp + lane;
  f4 acc[2][NBW];
  #pragma unroll
  for (int g = 0; g < 2; ++g)
    #pragma unroll
    for (int j = 0; j < NBW; ++j)
      acc[g][j] = (f4){0.f, 0.f, 0.f, 0.f};

  const unsigned* sA0 = &smA[lr][0];
  const unsigned* sA1 = &smA[lr + 16][0];
  #pragma unroll
  for (int ks = 0; ks < 4; ++ks){
    short8 a0 = *(const short8*)(sA0 + q*4 + ks*16);
    short8 a1 = *(const short8*)(sA1 + q*4 + ks*16);
    #pragma unroll
    for (int j = 0; j < NBW; ++j){
      int nb = wv * NBW + j;
      short8 b = pb[(ks * NB16 + nb) * 64];
      acc[0][j] = __builtin_amdgcn_mfma_f32_16x16x32_bf16(a0, b, acc[0][j], 0, 0, 0);
      acc[1][j] = __builtin_amdgcn_mfma_f32_16x16x32_bf16(a1, b, acc[1][j], 0, 0, 0);
    }
  }
  #pragma unroll
  for (int ks = 0; ks < 4; ++ks){
    short8 a0 = *(const short8*)(Xb + (size_t)(m0 + lr) * 64 + q*4 + ks*16);
    short8 a1 = *(const short8*)(Xb + (size_t)(m0 + lr + 16) * 64 + q*4 + ks*16);
    #pragma unroll
    for (int j = 0; j < NBW; ++j){
      int nb = wv * NBW + j;
      short8 b = pb[((4 + ks) * NB16 + nb) * 64];
      acc[0][j] = __builtin_amdgcn_mfma_f32_16x16x32_bf16(a0, b, acc[0][j], 0, 0, 0);
      acc[1][j] = __builtin_amdgcn_mfma_f32_16x16x32_bf16(a1, b, acc[1][j], 0, 0, 0);
    }
  }

  // ---- epilogue: C/D layout col=lane&15, row=(lane>>4)*4+reg ----
  #pragma unroll
  for (int j = 0; j < NBW; ++j){
    int col = (wv * NBW + j) * 16 + lr;
    float S = 1.f, T;
    if constexpr (DO_BN){
      float s = bg[col] * rsqrtf(bv[col] + 1e-5f);
      S = s;
      T = (bias[col] - bm[col]) * s + bb[col];
    } else {
      T = bias[col];
    }
    #pragma unroll
    for (int r = 0; r < 4; ++r){
      int row = m0 + q * 4 + r;
      float y0 = acc[0][j][r] * S + T;
      float y1 = acc[1][j][r] * S + T;
      if constexpr (DO_BN){
        y0 = y0 > 0.f ? y0 : 0.f;
        y1 = y1 > 0.f ? y1 : 0.f;
        OutB[(size_t)row * DOUT + col] = f2bf(y0);
        OutB[(size_t)(row + 16) * DOUT + col] = f2bf(y1);
      } else {
        OutF[(size_t)row * DOUT + col] = y0;
        OutF[(size_t)(row + 16) * DOUT + col] = y1;
      }
    }
  }
}

extern "C" void kernel_launch(void* const* d_in, const int* in_sizes, int n_in,
                              void* d_out, int out_size, void* d_ws, size_t ws_size,
                              hipStream_t stream){
  const float* x = (const float*)d_in[0];
  const int* ei = (const int*)d_in[1];
  const float* Wl0 = (const float*)d_in[2];
  const float* Wr0 = (const float*)d_in[3];
  const float* bl0 = (const float*)d_in[4];
  const float* Wl1 = (const float*)d_in[5];
  const float* Wr1 = (const float*)d_in[6];
  const float* bl1 = (const float*)d_in[7];
  const float* Wl2 = (const float*)d_in[8];
  const float* Wr2 = (const float*)d_in[9];
  const float* bl2 = (const float*)d_in[10];
  const float* g0 = (const float*)d_in[11];
  const float* b0 = (const float*)d_in[12];
  const float* bm0 = (const float*)d_in[13];
  const float* bv0 = (const float*)d_in[14];
  const float* g1 = (const float*)d_in[15];
  const float* b1 = (const float*)d_in[16];
  const float* bm1 = (const float*)d_in[17];
  const float* bv1 = (const float*)d_in[18];

  // ws layout (~37.4 MB <= 58 MB proven): rp2 + ss + bp0/1/2 + xb (aliased with h2).
  // Aliasing timeline: k_cvt writes xb; L0 reads xb -> h1 (d_out); L1 reads h1 ->
  // writes h2 over xb (xb dead); L2 reads h2 -> writes d_out (h1 dead). d_out
  // scratch (cnt2/pos2/bsum/boff) is dead before L0 writes h1 into d_out.
  const size_t REQUIRED = 38600000;
  if (ws_size < REQUIRED){
    k_sentinel<<<(out_size + 255) / 256, 256, 0, stream>>>((float*)d_out, out_size);
    return;
  }

  char* w = (char*)d_ws;
  size_t off = 0;
  auto alloc = [&](size_t bytes) -> char* {
    char* p = w + off; off = (off + bytes + 255) & ~(size_t)255; return p;
  };
  int* rp2 = (int*)alloc((size_t)(LEN + 1) * 4);
  int* ss  = (int*)alloc((size_t)NE * 4);
  unsigned short* bp0 = (unsigned short*)alloc(8 * 8 * 64 * 8 * 2);
  unsigned short* bp1 = (unsigned short*)alloc(8 * 8 * 64 * 8 * 2);
  unsigned short* bp2 = (unsigned short*)alloc(8 * 4 * 64 * 8 * 2);
  unsigned* xb = (unsigned*)alloc((size_t)NN * 64 * 4);   // bf16x2 x; later reused as h2
  unsigned short* h2 = (unsigned short*)xb;

  char* ow = (char*)d_out;
  size_t ooff = 0;
  auto oalloc = [&](size_t bytes) -> char* {
    char* p = ow + ooff; ooff = (ooff + bytes + 255) & ~(size_t)255; return p;
  };
  int* cnt2 = (int*)oalloc((size_t)LEN * 4);
  int* pos2 = (int*)oalloc((size_t)LEN * 4);
  int* bsum = (int*)oalloc(NB_SCAN * 4);
  int* boff = (int*)oalloc(NB_SCAN * 4);
  unsigned short* h1 = (unsigned short*)d_out;            // 25.6 MB, exactly d_out

  const int* srcI = ei;
  const int* dstI = ei + NE;

  hipMemsetAsync(cnt2, 0, (size_t)LEN * 4, stream);
  k_cvt<<<(NN * 16 + 255) / 256, 256, 0, stream>>>(x, xb);
  k_hist<<<(NE + 255) / 256, 256, 0, stream>>>(srcI, dstI, cnt2);
  k_bsum<<<NB_SCAN, 256, 0, stream>>>(cnt2, bsum, LEN);
  k_scanp<<<1, 256, 0, stream>>>(bsum, boff, NB_SCAN);
  k_scanf<<<NB_SCAN, 256, 0, stream>>>(cnt2, boff, rp2, pos2, LEN);
  k_scatter<<<(NE + 255) / 256, 256, 0, stream>>>(srcI, dstI, pos2, ss);
  k_pack<8><<<16, 256, 0, stream>>>(Wl0, Wr0, bp0);
  k_pack<8><<<16, 256, 0, stream>>>(Wl1, Wr1, bp1);
  k_pack<4><<<8, 256, 0, stream>>>(Wl2, Wr2, bp2);

  k_fused<8, true ><<<3125, 256, 0, stream>>>(xb, rp2, ss, bp0,
      bl0, g0, b0, bm0, bv0, h1, nullptr);
  k_fused<8, true ><<<3125, 256, 0, stream>>>((const unsigned*)h1, rp2, ss, bp1,
      bl1, g1, b1, bm1, bv1, h2, nullptr);
  k_fused<4, false><<<3125, 256, 0, stream>>>((const unsigned*)h2, rp2, ss, bp2,
      bl2, nullptr, nullptr, nullptr, nullptr, nullptr, (float*)d_out);
}

// Round 7
// 769.167 us; speedup vs baseline: 1.3183x; 1.3183x over previous
//
#include <hip/hip_runtime.h>

#define NN 100000
#define NE 1600000
#define DIM 128
#define NT 13            // src tiles: src>>13 -> 8192 rows = 2 MB bf16 per tile (fits 4 MB L2)
#define SH 13
#define LEN (NN * NT)    // 1,300,000 bucket counters, tile-major: idx = tt*NN + dst
#define NB_SCAN ((LEN + 1023) / 1024)

typedef __attribute__((ext_vector_type(8))) short short8;
typedef __attribute__((ext_vector_type(4))) float f4;
typedef __attribute__((ext_vector_type(4))) unsigned u4;

__device__ __forceinline__ unsigned short f2bf(float f){
  unsigned x = __float_as_uint(f);
  x += 0x7fffu + ((x >> 16) & 1u);
  return (unsigned short)(x >> 16);
}
__device__ __forceinline__ unsigned pack2(float lo, float hi){
  return ((unsigned)f2bf(hi) << 16) | (unsigned)f2bf(lo);
}
__device__ __forceinline__ float blo(unsigned u){ return __uint_as_float(u << 16); }
__device__ __forceinline__ float bhi(unsigned u){ return __uint_as_float(u & 0xffff0000u); }

// ---------------- fallback sentinel (ws too small diagnostic) ----------------
__global__ void k_sentinel(float* __restrict__ out, int n){
  int i = blockIdx.x * blockDim.x + threadIdx.x;
  if (i < n) out[i] = 12345.0f;
}

// ---------------- x fp32 -> bf16x2 (each thread: 8 floats -> 16 B out) ------
__global__ void k_cvt(const float* __restrict__ x, unsigned* __restrict__ xb){
  int i = blockIdx.x * blockDim.x + threadIdx.x;   // i < NN*16
  if (i >= NN * 16) return;
  f4 a = ((const f4*)x)[2 * i];
  f4 b = ((const f4*)x)[2 * i + 1];
  u4 o;
  o[0] = pack2(a[0], a[1]); o[1] = pack2(a[2], a[3]);
  o[2] = pack2(b[0], b[1]); o[3] = pack2(b[2], b[3]);
  ((u4*)xb)[i] = o;
}

// ---------------- bucketed CSR build (tile-major) ----------------
__global__ void k_hist(const int* __restrict__ src, const int* __restrict__ dst,
                       int* __restrict__ cnt){
  int i = blockIdx.x * blockDim.x + threadIdx.x;
  if (i < NE) atomicAdd(&cnt[(src[i] >> SH) * NN + dst[i]], 1);
}

__global__ void k_bsum(const int* __restrict__ cnt, int* __restrict__ bsum, int len){
  __shared__ int sh[256];
  int t = threadIdx.x, b = blockIdx.x;
  int base = b * 1024 + t * 4;
  int s = 0;
  #pragma unroll
  for (int j = 0; j < 4; ++j){ int i = base + j; if (i < len) s += cnt[i]; }
  sh[t] = s; __syncthreads();
  for (int off = 128; off > 0; off >>= 1){
    if (t < off) sh[t] += sh[t + off];
    __syncthreads();
  }
  if (t == 0) bsum[b] = sh[0];
}

__global__ void k_scanp(const int* __restrict__ bsum, int* __restrict__ boff, int nb){
  __shared__ int sh[256];
  int t = threadIdx.x;
  int chunk = (nb + 255) / 256;
  int s = 0;
  for (int j = 0; j < chunk; ++j){ int i = t * chunk + j; if (i < nb) s += bsum[i]; }
  sh[t] = s; __syncthreads();
  int tin = s;
  for (int off = 1; off < 256; off <<= 1){
    int u = (t >= off) ? sh[t - off] : 0;
    __syncthreads();
    sh[t] += u;
    __syncthreads();
  }
  int run = sh[t] - tin;
  for (int j = 0; j < chunk; ++j){
    int i = t * chunk + j;
    if (i < nb){ boff[i] = run; run += bsum[i]; }
  }
}

__global__ void k_scanf(const int* __restrict__ cnt, const int* __restrict__ boff,
                        int* __restrict__ rp, int* __restrict__ pos, int len){
  __shared__ int sh[256];
  int t = threadIdx.x, b = blockIdx.x;
  int base = b * 1024 + t * 4;
  int c[4]; int s = 0;
  #pragma unroll
  for (int j = 0; j < 4; ++j){ int i = base + j; c[j] = (i < len) ? cnt[i] : 0; s += c[j]; }
  sh[t] = s; __syncthreads();
  int tin = s;
  for (int off = 1; off < 256; off <<= 1){
    int u = (t >= off) ? sh[t - off] : 0;
    __syncthreads();
    sh[t] += u;
    __syncthreads();
  }
  int run = boff[b] + sh[t] - tin;
  #pragma unroll
  for (int j = 0; j < 4; ++j){
    int i = base + j;
    if (i < len){
      rp[i] = run; pos[i] = run; run += c[j];
      if (i == len - 1) rp[len] = run;
    }
  }
}

// pack src (17b) | (dst&7)<<20 — wave row-groups are 8-aligned
__global__ void k_scatter(const int* __restrict__ src, const int* __restrict__ dst,
                          int* __restrict__ pos, int* __restrict__ ss){
  int i = blockIdx.x * blockDim.x + threadIdx.x;
  if (i < NE){
    int s = src[i], d = dst[i];
    int p = atomicAdd(&pos[(s >> SH) * NN + d], 1);
    ss[p] = s | ((d & 7) << 20);
  }
}

// ---------------- W packing: fp32 -> bf16 MFMA B-fragment order ----------------
template<int NB16>
__global__ void k_pack(const float* __restrict__ Wl,
                       const float* __restrict__ Wr,
                       unsigned short* __restrict__ Bp){
  constexpr int DOUT = NB16 * 16;
  int idx = blockIdx.x * blockDim.x + threadIdx.x;
  if (idx >= 8 * NB16 * 64) return;
  int lane = idx & 63;
  int nb = (idx >> 6) % NB16;
  int ks = idx / (64 * NB16);
  int n = nb * 16 + (lane & 15);
  int k0 = ks * 32 + (lane >> 4) * 8;
  short8 v;
  #pragma unroll
  for (int j = 0; j < 8; ++j){
    int k = k0 + j;
    float w = (k < 128) ? Wl[k * DOUT + n] : Wr[(k - 128) * DOUT + n];
    v[j] = (short)f2bf(w);
  }
  ((short8*)Bp)[idx] = v;
}

// ---------------- fused tiled mean-aggregate + dual-GEMM (+BN+ReLU) ----------------
// Phase 1: per (wave, tile) ONE contiguous ss range covering the wave's 8 rows
// (tile-major CSR). 4-wide MLP gather batches; row tag via readfirstlane ->
// scalar switch into register accumulators. Phase 2: MFMA 16x16x32 bf16.
template<int NB16, bool DO_BN>
__global__ __launch_bounds__(256)
void k_fused(const unsigned* __restrict__ Xb,
             const int* __restrict__ rp2, const int* __restrict__ ss,
             const unsigned short* __restrict__ Bp,
             const float* __restrict__ bias,
             const float* __restrict__ bg, const float* __restrict__ bb,
             const float* __restrict__ bm, const float* __restrict__ bv,
             unsigned short* __restrict__ OutB, float* __restrict__ OutF){
  constexpr int DOUT = NB16 * 16;
  constexpr int NBW = NB16 / 4;
  __shared__ unsigned smA[32][68];
  const int t = threadIdx.x;
  const int lane = t & 63;
  const int wv = t >> 6;
  const int m0 = blockIdx.x * 32;
  const int row0 = m0 + wv * 8;

  // ---- phase 1: tiled mean aggregation, register accumulators ----
  float ax[8], ay[8];
  int cn[8];
  #pragma unroll
  for (int rr = 0; rr < 8; ++rr){ ax[rr] = 0.f; ay[rr] = 0.f; cn[rr] = 0; }

  auto acc1 = [&](int ee, unsigned u){
    float lo = blo(u), hi = bhi(u);
    switch (ee >> 20){             // ee is SGPR (readfirstlane) -> uniform branch
      case 0: ax[0] += lo; ay[0] += hi; ++cn[0]; break;
      case 1: ax[1] += lo; ay[1] += hi; ++cn[1]; break;
      case 2: ax[2] += lo; ay[2] += hi; ++cn[2]; break;
      case 3: ax[3] += lo; ay[3] += hi; ++cn[3]; break;
      case 4: ax[4] += lo; ay[4] += hi; ++cn[4]; break;
      case 5: ax[5] += lo; ay[5] += hi; ++cn[5]; break;
      case 6: ax[6] += lo; ay[6] += hi; ++cn[6]; break;
      default: ax[7] += lo; ay[7] += hi; ++cn[7]; break;
    }
  };

  for (int tt = 0; tt < NT; ++tt){
    int beg = __builtin_amdgcn_readfirstlane(rp2[tt * NN + row0]);
    int end = __builtin_amdgcn_readfirstlane(rp2[tt * NN + row0 + 8]);
    int e = beg;
    for (; e + 4 <= end; e += 4){
      int e0 = __builtin_amdgcn_readfirstlane(ss[e]);
      int e1 = __builtin_amdgcn_readfirstlane(ss[e + 1]);
      int e2 = __builtin_amdgcn_readfirstlane(ss[e + 2]);
      int e3 = __builtin_amdgcn_readfirstlane(ss[e + 3]);
      unsigned u0 = Xb[(size_t)(e0 & 0xFFFFF) * 64 + lane];
      unsigned u1 = Xb[(size_t)(e1 & 0xFFFFF) * 64 + lane];
      unsigned u2 = Xb[(size_t)(e2 & 0xFFFFF) * 64 + lane];
      unsigned u3 = Xb[(size_t)(e3 & 0xFFFFF) * 64 + lane];
      acc1(e0, u0); acc1(e1, u1); acc1(e2, u2); acc1(e3, u3);
    }
    for (; e < end; ++e){
      int e0 = __builtin_amdgcn_readfirstlane(ss[e]);
      unsigned u0 = Xb[(size_t)(e0 & 0xFFFFF) * 64 + lane];
      acc1(e0, u0);
    }
  }
  #pragma unroll
  for (int rr = 0; rr < 8; ++rr){
    float inv = (cn[rr] > 0) ? 1.f / (float)cn[rr] : 0.f;
    smA[wv * 8 + rr][lane] = pack2(ax[rr] * inv, ay[rr] * inv);
  }
  __syncthreads();

  // ---- phase 2: dual GEMM (K 0..127 = mean@Wl from LDS, 128..255 = h@Wr) ----
  const int q = lane >> 4, lr = lane & 15;
  const short8* pb = (const short8*)Bp + lane;
  f4 acc[2][NBW];
  #pragma unroll
  for (int g = 0; g < 2; ++g)
    #pragma unroll
    for (int j = 0; j < NBW; ++j)
      acc[g][j] = (f4){0.f, 0.f, 0.f, 0.f};

  const unsigned* sA0 = &smA[lr][0];
  const unsigned* sA1 = &smA[lr + 16][0];
  #pragma unroll
  for (int ks = 0; ks < 4; ++ks){
    short8 a0 = *(const short8*)(sA0 + q*4 + ks*16);
    short8 a1 = *(const short8*)(sA1 + q*4 + ks*16);
    #pragma unroll
    for (int j = 0; j < NBW; ++j){
      int nb = wv * NBW + j;
      short8 b = pb[(ks * NB16 + nb) * 64];
      acc[0][j] = __builtin_amdgcn_mfma_f32_16x16x32_bf16(a0, b, acc[0][j], 0, 0, 0);
      acc[1][j] = __builtin_amdgcn_mfma_f32_16x16x32_bf16(a1, b, acc[1][j], 0, 0, 0);
    }
  }
  #pragma unroll
  for (int ks = 0; ks < 4; ++ks){
    short8 a0 = *(const short8*)(Xb + (size_t)(m0 + lr) * 64 + q*4 + ks*16);
    short8 a1 = *(const short8*)(Xb + (size_t)(m0 + lr + 16) * 64 + q*4 + ks*16);
    #pragma unroll
    for (int j = 0; j < NBW; ++j){
      int nb = wv * NBW + j;
      short8 b = pb[((4 + ks) * NB16 + nb) * 64];
      acc[0][j] = __builtin_amdgcn_mfma_f32_16x16x32_bf16(a0, b, acc[0][j], 0, 0, 0);
      acc[1][j] = __builtin_amdgcn_mfma_f32_16x16x32_bf16(a1, b, acc[1][j], 0, 0, 0);
    }
  }

  // ---- epilogue: C/D layout col=lane&15, row=(lane>>4)*4+reg ----
  #pragma unroll
  for (int j = 0; j < NBW; ++j){
    int col = (wv * NBW + j) * 16 + lr;
    float S = 1.f, T;
    if constexpr (DO_BN){
      float s = bg[col] * rsqrtf(bv[col] + 1e-5f);
      S = s;
      T = (bias[col] - bm[col]) * s + bb[col];
    } else {
      T = bias[col];
    }
    #pragma unroll
    for (int r = 0; r < 4; ++r){
      int row = m0 + q * 4 + r;
      float y0 = acc[0][j][r] * S + T;
      float y1 = acc[1][j][r] * S + T;
      if constexpr (DO_BN){
        y0 = y0 > 0.f ? y0 : 0.f;
        y1 = y1 > 0.f ? y1 : 0.f;
        OutB[(size_t)row * DOUT + col] = f2bf(y0);
        OutB[(size_t)(row + 16) * DOUT + col] = f2bf(y1);
      } else {
        OutF[(size_t)row * DOUT + col] = y0;
        OutF[(size_t)(row + 16) * DOUT + col] = y1;
      }
    }
  }
}

extern "C" void kernel_launch(void* const* d_in, const int* in_sizes, int n_in,
                              void* d_out, int out_size, void* d_ws, size_t ws_size,
                              hipStream_t stream){
  const float* x = (const float*)d_in[0];
  const int* ei = (const int*)d_in[1];
  const float* Wl0 = (const float*)d_in[2];
  const float* Wr0 = (const float*)d_in[3];
  const float* bl0 = (const float*)d_in[4];
  const float* Wl1 = (const float*)d_in[5];
  const float* Wr1 = (const float*)d_in[6];
  const float* bl1 = (const float*)d_in[7];
  const float* Wl2 = (const float*)d_in[8];
  const float* Wr2 = (const float*)d_in[9];
  const float* bl2 = (const float*)d_in[10];
  const float* g0 = (const float*)d_in[11];
  const float* b0 = (const float*)d_in[12];
  const float* bm0 = (const float*)d_in[13];
  const float* bv0 = (const float*)d_in[14];
  const float* g1 = (const float*)d_in[15];
  const float* b1 = (const float*)d_in[16];
  const float* bm1 = (const float*)d_in[17];
  const float* bv1 = (const float*)d_in[18];

  const size_t REQUIRED = 38600000;
  if (ws_size < REQUIRED){
    k_sentinel<<<(out_size + 255) / 256, 256, 0, stream>>>((float*)d_out, out_size);
    return;
  }

  char* w = (char*)d_ws;
  size_t off = 0;
  auto alloc = [&](size_t bytes) -> char* {
    char* p = w + off; off = (off + bytes + 255) & ~(size_t)255; return p;
  };
  int* rp2 = (int*)alloc((size_t)(LEN + 1) * 4);
  int* ss  = (int*)alloc((size_t)NE * 4);
  unsigned short* bp0 = (unsigned short*)alloc(8 * 8 * 64 * 8 * 2);
  unsigned short* bp1 = (unsigned short*)alloc(8 * 8 * 64 * 8 * 2);
  unsigned short* bp2 = (unsigned short*)alloc(8 * 4 * 64 * 8 * 2);
  unsigned* xb = (unsigned*)alloc((size_t)NN * 64 * 4);   // bf16x2 x; later reused as h2
  unsigned short* h2 = (unsigned short*)xb;

  char* ow = (char*)d_out;
  size_t ooff = 0;
  auto oalloc = [&](size_t bytes) -> char* {
    char* p = ow + ooff; ooff = (ooff + bytes + 255) & ~(size_t)255; return p;
  };
  int* cnt2 = (int*)oalloc((size_t)LEN * 4);
  int* pos2 = (int*)oalloc((size_t)LEN * 4);
  int* bsum = (int*)oalloc(NB_SCAN * 4);
  int* boff = (int*)oalloc(NB_SCAN * 4);
  unsigned short* h1 = (unsigned short*)d_out;            // 25.6 MB, exactly d_out

  const int* srcI = ei;
  const int* dstI = ei + NE;

  hipMemsetAsync(cnt2, 0, (size_t)LEN * 4, stream);
  k_cvt<<<(NN * 16 + 255) / 256, 256, 0, stream>>>(x, xb);
  k_hist<<<(NE + 255) / 256, 256, 0, stream>>>(srcI, dstI, cnt2);
  k_bsum<<<NB_SCAN, 256, 0, stream>>>(cnt2, bsum, LEN);
  k_scanp<<<1, 256, 0, stream>>>(bsum, boff, NB_SCAN);
  k_scanf<<<NB_SCAN, 256, 0, stream>>>(cnt2, boff, rp2, pos2, LEN);
  k_scatter<<<(NE + 255) / 256, 256, 0, stream>>>(srcI, dstI, pos2, ss);
  k_pack<8><<<16, 256, 0, stream>>>(Wl0, Wr0, bp0);
  k_pack<8><<<16, 256, 0, stream>>>(Wl1, Wr1, bp1);
  k_pack<4><<<8, 256, 0, stream>>>(Wl2, Wr2, bp2);

  k_fused<8, true ><<<3125, 256, 0, stream>>>(xb, rp2, ss, bp0,
      bl0, g0, b0, bm0, bv0, h1, nullptr);
  k_fused<8, true ><<<3125, 256, 0, stream>>>((const unsigned*)h1, rp2, ss, bp1,
      bl1, g1, b1, bm1, bv1, h2, nullptr);
  k_fused<4, false><<<3125, 256, 0, stream>>>((const unsigned*)h2, rp2, ss, bp2,
      bl2, nullptr, nullptr, nullptr, nullptr, nullptr, (float*)d_out);
}